// Round 10
// baseline (195.179 us; speedup 1.0000x reference)
//
#include <hip/hip_runtime.h>
#include <hip/hip_bf16.h>

#define N_SEQ 4096
#define DIM   128
#define NH    4
#define DH    32
#define BATCH 4

// scale = (1/sqrt(32)) * log2(e): softmax computed in exp2 domain
#define QSCALE 0.25503495870989204f

typedef __bf16 bf16x8 __attribute__((ext_vector_type(8)));
typedef __bf16 bf16x2 __attribute__((ext_vector_type(2)));
typedef __bf16 bf16x4 __attribute__((ext_vector_type(4)));
typedef float  f32x4  __attribute__((ext_vector_type(4)));

#define MFMA(a, b, c) __builtin_amdgcn_mfma_f32_16x16x32_bf16((a), (b), (c), 0, 0, 0)

static __device__ __forceinline__ bf16x8 cvt8(const float* __restrict__ p) {
    const float4* f4 = reinterpret_cast<const float4*>(p);
    float4 a = f4[0], b = f4[1];
    bf16x8 r;
    r[0] = (__bf16)a.x; r[1] = (__bf16)a.y; r[2] = (__bf16)a.z; r[3] = (__bf16)a.w;
    r[4] = (__bf16)b.x; r[5] = (__bf16)b.y; r[6] = (__bf16)b.z; r[7] = (__bf16)b.w;
    return r;
}

static __device__ __forceinline__ f32x4 exp4(f32x4 s) {
    f32x4 r;
    r[0] = __builtin_amdgcn_exp2f(s[0]);
    r[1] = __builtin_amdgcn_exp2f(s[1]);
    r[2] = __builtin_amdgcn_exp2f(s[2]);
    r[3] = __builtin_amdgcn_exp2f(s[3]);
    return r;
}

// adjacent-pair writes -> compiler can fuse into packed bf16 converts
static __device__ __forceinline__ bf16x8 pack8(f32x4 a, f32x4 b) {
    bf16x8 o;
    o[0] = (__bf16)a[0]; o[1] = (__bf16)a[1];
    o[2] = (__bf16)a[2]; o[3] = (__bf16)a[3];
    o[4] = (__bf16)b[0]; o[5] = (__bf16)b[1];
    o[6] = (__bf16)b[2]; o[7] = (__bf16)b[3];
    return o;
}

// ---------------------------------------------------------------------------
// Kernel 1: fused QKV projection, operand-SWAPPED MFMA (A=W rows, B=x rows).
// (unchanged — held control)
// ---------------------------------------------------------------------------
__global__ __launch_bounds__(256) void proj_qkv(
    const float* __restrict__ xq, const float* __restrict__ xk, const float* __restrict__ xv,
    const float* __restrict__ Wq, const float* __restrict__ Wk, const float* __restrict__ Wv,
    const float* __restrict__ bq, const float* __restrict__ bk, const float* __restrict__ bv,
    __bf16* __restrict__ Qs, __bf16* __restrict__ Kb, __bf16* __restrict__ Vt)
{
    __shared__ __align__(16) char wlds[34816];        // 128 rows x 272 B
    const int z = blockIdx.z;
    const float* x    = (z == 0) ? xq : ((z == 1) ? xk : xv);
    const float* Wf   = (z == 0) ? Wq : ((z == 1) ? Wk : Wv);
    const float* bias = (z == 0) ? bq : ((z == 1) ? bk : bv);
    const int b    = blockIdx.y;
    const int tid  = threadIdx.x;
    const int wave = tid >> 6, lane = tid & 63;
    const int quad = lane >> 4, l15 = lane & 15;
    const int n0   = blockIdx.x * 64 + wave * 16;

    {   // stage W (fp32 -> bf16) into LDS: thread = half-row
        const int r = tid >> 1, half = tid & 1;
        const float* wsrc = Wf + r * DIM + half * 64;
        char* wdst = wlds + r * 272 + half * 128;
        #pragma unroll
        for (int i = 0; i < 8; i++)
            *(bf16x8*)(wdst + i * 16) = cvt8(wsrc + i * 8);
    }

    bf16x8 a[4];
    const float* xrow = x + (b * N_SEQ + n0 + l15) * DIM + quad * 8;
    a[0] = cvt8(xrow);      a[1] = cvt8(xrow + 32);
    a[2] = cvt8(xrow + 64); a[3] = cvt8(xrow + 96);
    __syncthreads();

    const int n = n0 + l15;                    // D col = n (swapped)
    for (int t = 0; t < 8; t++) {
        const char* wr = wlds + (t * 16 + l15) * 272 + quad * 16;
        bf16x8 w0 = *(const bf16x8*)(wr);
        bf16x8 w1 = *(const bf16x8*)(wr + 64);
        bf16x8 w2 = *(const bf16x8*)(wr + 128);
        bf16x8 w3 = *(const bf16x8*)(wr + 192);

        f32x4 acc = {0.f, 0.f, 0.f, 0.f};
        acc = MFMA(w0, a[0], acc);
        acc = MFMA(w1, a[1], acc);
        acc = MFMA(w2, a[2], acc);
        acc = MFMA(w3, a[3], acc);

        const int d0 = t * 16 + quad * 4;      // D row = d0 + r
        if (z == 0) {
            const int h = d0 >> 5, dh0 = d0 & 31;
            bf16x4 q4;
            #pragma unroll
            for (int r = 0; r < 4; r++)
                q4[r] = (__bf16)((acc[r] + bias[d0 + r]) * QSCALE);
            *(bf16x4*)(Qs + ((b * NH + h) * N_SEQ + n) * DH + dh0) = q4;
        } else if (z == 1) {
            const int h = d0 >> 5, dh0 = d0 & 31;
            bf16x4 k4;
            #pragma unroll
            for (int r = 0; r < 4; r++)
                k4[r] = (__bf16)(acc[r] + bias[d0 + r]);
            *(bf16x4*)(Kb + ((b * NH + h) * N_SEQ + n) * DH + dh0) = k4;
        } else {
            const int nl = n & 63;
            const int np = (n & ~63) | (nl & 35) | ((nl & 12) << 1) | ((nl & 16) >> 2);
            #pragma unroll
            for (int r = 0; r < 4; r++) {
                const int d = d0 + r, h = d >> 5, dh = d & 31;
                Vt[((b * NH + h) * DH + dh) * N_SEQ + np] = (__bf16)(acc[r] + bias[d]);
            }
        }
    }
}

// ---------------------------------------------------------------------------
// Kernel 2: attention, 8-wave blocks = 2 query halves x 4-way split-K.
// Block = (head bh, 128 queries), 512 threads.  Wave w: qh=w&1 (64 q),
// kh=w>>2... w>>1 (1024 keys).  4 waves/SIMD (2 blocks/CU) interleave the
// serial chain (ds_read K -> S-MFMA -> quarter-rate exp2 -> pack -> PV-MFMA)
// that left VALU at 47% with only 2 waves/SIMD (R9).
// Per iter: 4 K-tiles (64x64B, stride 80) + 4 V-tiles (32x128B, stride 144)
// staged double-buffered, one barrier/iter.  P stays in registers (Vt
// key-permuted so score regs pack straight into the PV B-fragment).
// Split-K combine: kh=1..3 waves dump ctx+l partials into the (dead) K/V
// LDS region, kh=0 combines + stores.  Softmax has no max subtraction, so
// split-K is exact fp32 reassociation.
// grid = 512 (bh=bid&15), LDS 77824 B, __launch_bounds__(512,4) caps VGPR 128.
// ---------------------------------------------------------------------------
__global__ __launch_bounds__(512, 4) void flash_attn(
    const __bf16* __restrict__ Qs, const __bf16* __restrict__ Kb,
    const __bf16* __restrict__ Vt, __bf16* __restrict__ ctxb)
{
    // K: 4 kh x 2 buf x 5120 = 40960 | V: 4 kh x 2 buf x 4608 = 36864
    // partials (post-loop, reuses K/V region): 2 qh x 3 kh x 64 lanes x 144
    __shared__ __align__(16) char smem[77824];
    char* const Kbase = smem;                  // + kh*10240 + cur*5120
    char* const Vbase = smem + 40960;          // + kh*9216  + cur*4608

    const int bid  = blockIdx.x;
    const int bh   = bid & 15;                 // consecutive blocks cycle heads
    const int qc   = bid >> 4;                 // 0..31, 128 queries each
    const int tid  = threadIdx.x;
    const int wave = tid >> 6, lane = tid & 63;
    const int quad = lane >> 4, l15 = lane & 15;
    const int qh   = wave & 1, kh = wave >> 1; // kh in 0..3
    const int n0   = qc * 128 + qh * 64;
    const int KH   = 1024;                     // keys per kh

    // Q B-fragments: 4 tiles of 16 queries
    const __bf16* Qp = Qs + (bh * N_SEQ + n0) * DH;
    bf16x8 qf[4];
    #pragma unroll
    for (int q = 0; q < 4; q++)
        qf[q] = *(const bf16x8*)(Qp + (q * 16 + l15) * DH + quad * 8);

    // staging: 512 threads cover 4 K-tiles + 4 V-tiles; thread does kh = khA, khA+2
    const int t8  = tid & 255, khA = tid >> 8;           // khA in {0,1}
    const int r_  = t8 >> 2,  c_  = t8 & 3;
    const __bf16* gK = Kb + (size_t)bh * N_SEQ * DH + (khA * KH + r_) * DH + c_ * 8;
    const __bf16* gV = Vt + ((size_t)bh * DH + (t8 >> 3)) * N_SEQ + khA * KH + (t8 & 7) * 8;
    const int kofsK = r_ * 80 + c_ * 16;
    const int kofsV = (t8 >> 3) * 144 + (t8 & 7) * 16;
    const int kStep2 = 2 * KH * DH;            // +2 kh groups in K elements
    char* const KldsA = Kbase + khA * 10240 + kofsK;
    char* const KldsB = Kbase + (khA + 2) * 10240 + kofsK;
    char* const VldsA = Vbase + khA * 9216 + kofsV;
    char* const VldsB = Vbase + (khA + 2) * 9216 + kofsV;

    {   // prologue: stage tile 0 of all 4 kh groups into buf 0
        bf16x8 k0 = *(const bf16x8*)(gK);
        bf16x8 k1 = *(const bf16x8*)(gK + kStep2);
        bf16x8 v0 = *(const bf16x8*)(gV);
        bf16x8 v1 = *(const bf16x8*)(gV + 2 * KH);
        *(bf16x8*)(KldsA) = k0;
        *(bf16x8*)(KldsB) = k1;
        *(bf16x8*)(VldsA) = v0;
        *(bf16x8*)(VldsB) = v1;
    }
    __syncthreads();

    char* const Kme = Kbase + kh * 10240;
    char* const Vme = Vbase + kh * 9216;

    f32x4 c[4][2];
    #pragma unroll
    for (int q = 0; q < 4; q++) { c[q][0] = f32x4{0.f,0.f,0.f,0.f}; c[q][1] = f32x4{0.f,0.f,0.f,0.f}; }
    float l[4] = {0.f, 0.f, 0.f, 0.f};
    const f32x4 z4 = {0.f,0.f,0.f,0.f};

    for (int kb = 0; kb < KH / 64; kb++) {     // 16 iters
        const int cur = kb & 1;
        const char* Kc = Kme + cur * 5120;
        const char* Vc = Vme + cur * 4608;

        // prefetch next 64-key tiles for all kh groups (wraps; harmless)
        const int kn = (kb + 1) & (KH / 64 - 1);
        bf16x8 krn0 = *(const bf16x8*)(gK + (size_t)(kn * 64) * DH);
        bf16x8 krn1 = *(const bf16x8*)(gK + (size_t)(kn * 64) * DH + kStep2);
        bf16x8 vrn0 = *(const bf16x8*)(gV + kn * 64);
        bf16x8 vrn1 = *(const bf16x8*)(gV + 2 * KH + kn * 64);

        // K A-frags (identity layout; rows 16b+l15)
        bf16x8 kf0 = *(const bf16x8*)(Kc + l15 * 80 + quad * 16);
        bf16x8 kf1 = *(const bf16x8*)(Kc + (16 + l15) * 80 + quad * 16);
        bf16x8 kf2 = *(const bf16x8*)(Kc + (32 + l15) * 80 + quad * 16);
        bf16x8 kf3 = *(const bf16x8*)(Kc + (48 + l15) * 80 + quad * 16);

        // scores + P (in registers) per query tile
        bf16x8 pf[4][2];
        #pragma unroll
        for (int q = 0; q < 4; q++) {
            f32x4 sa = MFMA(kf0, qf[q], z4);
            f32x4 sb = MFMA(kf1, qf[q], z4);
            f32x4 sc = MFMA(kf2, qf[q], z4);
            f32x4 sd = MFMA(kf3, qf[q], z4);
            f32x4 ea = exp4(sa), eb = exp4(sb), ec = exp4(sc), ed = exp4(sd);
            l[q] += ((ea[0]+ea[1])+(ea[2]+ea[3])) + ((eb[0]+eb[1])+(eb[2]+eb[3]))
                  + ((ec[0]+ec[1])+(ec[2]+ec[3])) + ((ed[0]+ed[1])+(ed[2]+ed[3]));
            pf[q][0] = pack8(ea, eb);          // keys g0
            pf[q][1] = pack8(ec, ed);          // keys g1
        }

        // V^T A-frags (stride 144, key-group g via +64)
        bf16x8 vf00 = *(const bf16x8*)(Vc + l15 * 144 + quad * 16);          // d0-15,  g0
        bf16x8 vf10 = *(const bf16x8*)(Vc + (16 + l15) * 144 + quad * 16);   // d16-31, g0
        bf16x8 vf01 = *(const bf16x8*)(Vc + l15 * 144 + 64 + quad * 16);     // d0-15,  g1
        bf16x8 vf11 = *(const bf16x8*)(Vc + (16 + l15) * 144 + 64 + quad * 16);

        #pragma unroll
        for (int q = 0; q < 4; q++) {
            c[q][0] = MFMA(vf00, pf[q][0], c[q][0]);
            c[q][1] = MFMA(vf10, pf[q][0], c[q][1]);
            c[q][0] = MFMA(vf01, pf[q][1], c[q][0]);
            c[q][1] = MFMA(vf11, pf[q][1], c[q][1]);
        }

        // stage next tiles into the other buffer
        *(bf16x8*)(KldsA + (cur ^ 1) * 5120) = krn0;
        *(bf16x8*)(KldsB + (cur ^ 1) * 5120) = krn1;
        *(bf16x8*)(VldsA + (cur ^ 1) * 4608) = vrn0;
        *(bf16x8*)(VldsB + (cur ^ 1) * 4608) = vrn1;
        __syncthreads();
    }

    // reduce l over quads (query = l15 preserved)
    #pragma unroll
    for (int q = 0; q < 4; q++) {
        l[q] += __shfl_xor(l[q], 16);
        l[q] += __shfl_xor(l[q], 32);
    }

    // split-K combine through (dead) K/V LDS region
    if (kh != 0) {
        char* dst = smem + ((qh * 3 + (kh - 1)) * 64 + lane) * 144;
        #pragma unroll
        for (int q = 0; q < 4; q++) {
            *(f32x4*)(dst + (q * 2 + 0) * 16) = c[q][0];
            *(f32x4*)(dst + (q * 2 + 1) * 16) = c[q][1];
        }
        f32x4 lv = {l[0], l[1], l[2], l[3]};
        *(f32x4*)(dst + 128) = lv;
    }
    __syncthreads();
    if (kh == 0) {
        #pragma unroll
        for (int m = 0; m < 3; m++) {
            const char* src = smem + ((qh * 3 + m) * 64 + lane) * 144;
            #pragma unroll
            for (int q = 0; q < 4; q++) {
                c[q][0] += *(const f32x4*)(src + (q * 2 + 0) * 16);
                c[q][1] += *(const f32x4*)(src + (q * 2 + 1) * 16);
            }
            f32x4 lp = *(const f32x4*)(src + 128);
            l[0] += lp[0]; l[1] += lp[1]; l[2] += lp[2]; l[3] += lp[3];
        }
        const int b = bh >> 2, h = bh & 3;
        #pragma unroll
        for (int q = 0; q < 4; q++) {
            const float inv = 1.0f / l[q];
            const int qg = n0 + q * 16 + l15;
            __bf16* dst = ctxb + ((size_t)(b * N_SEQ + qg)) * DIM + h * DH + quad * 4;
            #pragma unroll
            for (int dt = 0; dt < 2; dt++) {
                f32x4 cc = c[q][dt];
                bf16x2 e0 = {(__bf16)(cc[0] * inv), (__bf16)(cc[1] * inv)};
                bf16x2 e1 = {(__bf16)(cc[2] * inv), (__bf16)(cc[3] * inv)};
                *(bf16x2*)(dst + dt * 16)     = e0;
                *(bf16x2*)(dst + dt * 16 + 2) = e1;
            }
        }
    }
}

// ---------------------------------------------------------------------------
// Kernel 3: output projection, operand-swapped + Wo staged in LDS.
// (unchanged — held control)
// ---------------------------------------------------------------------------
__global__ __launch_bounds__(256) void out_proj(
    const __bf16* __restrict__ ctxb, const float* __restrict__ Wo,
    const float* __restrict__ bo, float* __restrict__ out)
{
    __shared__ __align__(16) char wlds[34816];
    const int b    = blockIdx.y;
    const int tid  = threadIdx.x;
    const int wave = tid >> 6, lane = tid & 63;
    const int quad = lane >> 4, l15 = lane & 15;
    const int n0   = blockIdx.x * 64 + wave * 16;

    {   // stage Wo (fp32 -> bf16) into LDS
        const int r = tid >> 1, half = tid & 1;
        const float* wsrc = Wo + r * DIM + half * 64;
        char* wdst = wlds + r * 272 + half * 128;
        #pragma unroll
        for (int i = 0; i < 8; i++)
            *(bf16x8*)(wdst + i * 16) = cvt8(wsrc + i * 8);
    }

    bf16x8 a[4];
    const __bf16* crow = ctxb + (b * N_SEQ + n0 + l15) * DIM + quad * 8;
    a[0] = *(const bf16x8*)(crow);
    a[1] = *(const bf16x8*)(crow + 32);
    a[2] = *(const bf16x8*)(crow + 64);
    a[3] = *(const bf16x8*)(crow + 96);
    __syncthreads();

    const int n = n0 + l15;
    for (int t = 0; t < 8; t++) {
        const char* wr = wlds + (t * 16 + l15) * 272 + quad * 16;
        bf16x8 w0 = *(const bf16x8*)(wr);
        bf16x8 w1 = *(const bf16x8*)(wr + 64);
        bf16x8 w2 = *(const bf16x8*)(wr + 128);
        bf16x8 w3 = *(const bf16x8*)(wr + 192);

        f32x4 acc = {0.f, 0.f, 0.f, 0.f};
        acc = MFMA(w0, a[0], acc);
        acc = MFMA(w1, a[1], acc);
        acc = MFMA(w2, a[2], acc);
        acc = MFMA(w3, a[3], acc);

        const int d0 = t * 16 + quad * 4;
        float4 o;
        o.x = acc[0] + bo[d0];
        o.y = acc[1] + bo[d0 + 1];
        o.z = acc[2] + bo[d0 + 2];
        o.w = acc[3] + bo[d0 + 3];
        *(float4*)(out + (b * N_SEQ + n) * DIM + d0) = o;
    }
}

// ---------------------------------------------------------------------------
extern "C" void kernel_launch(void* const* d_in, const int* in_sizes, int n_in,
                              void* d_out, int out_size, void* d_ws, size_t ws_size,
                              hipStream_t stream)
{
    const float* query = (const float*)d_in[0];
    const float* key   = (const float*)d_in[1];
    const float* value = (const float*)d_in[2];
    const float* Wq = (const float*)d_in[3];
    const float* bq = (const float*)d_in[4];
    const float* Wk = (const float*)d_in[5];
    const float* bk = (const float*)d_in[6];
    const float* Wv = (const float*)d_in[7];
    const float* bv = (const float*)d_in[8];
    const float* Wo = (const float*)d_in[9];
    const float* bo = (const float*)d_in[10];
    float* out = (float*)d_out;

    char* ws = (char*)d_ws;
    const size_t e = (size_t)BATCH * N_SEQ * DIM;   // 2,097,152 elements
    __bf16* Qs   = (__bf16*)(ws);                   // 4 MB  [B,H,N,32] scaled
    __bf16* Kb   = (__bf16*)(ws + 2 * e);           // 4 MB  [B,H,N,32] identity
    __bf16* Vt   = (__bf16*)(ws + 4 * e);           // 4 MB  [B,H,32,N] key-permuted
    __bf16* ctxb = (__bf16*)(ws + 6 * e);           // 4 MB  [B,N,128]

    proj_qkv<<<dim3(64, BATCH, 3), 256, 0, stream>>>(
        query, key, value, Wq, Wk, Wv, bq, bk, bv, Qs, Kb, Vt);
    flash_attn<<<dim3(512), 512, 0, stream>>>(Qs, Kb, Vt, ctxb);
    out_proj<<<dim3(64, BATCH), 256, 0, stream>>>(ctxb, Wo, bo, out);
}

// Round 11
// 157.086 us; speedup vs baseline: 1.2425x; 1.2425x over previous
//
#include <hip/hip_runtime.h>
#include <hip/hip_bf16.h>

#define N_SEQ 4096
#define DIM   128
#define NH    4
#define DH    32
#define BATCH 4

// scale = (1/sqrt(32)) * log2(e): softmax computed in exp2 domain
#define QSCALE 0.25503495870989204f

typedef __bf16 bf16x8 __attribute__((ext_vector_type(8)));
typedef __bf16 bf16x2 __attribute__((ext_vector_type(2)));
typedef __bf16 bf16x4 __attribute__((ext_vector_type(4)));
typedef float  f32x4  __attribute__((ext_vector_type(4)));

#define MFMA(a, b, c) __builtin_amdgcn_mfma_f32_16x16x32_bf16((a), (b), (c), 0, 0, 0)

static __device__ __forceinline__ bf16x8 cvt8(const float* __restrict__ p) {
    const float4* f4 = reinterpret_cast<const float4*>(p);
    float4 a = f4[0], b = f4[1];
    bf16x8 r;
    r[0] = (__bf16)a.x; r[1] = (__bf16)a.y; r[2] = (__bf16)a.z; r[3] = (__bf16)a.w;
    r[4] = (__bf16)b.x; r[5] = (__bf16)b.y; r[6] = (__bf16)b.z; r[7] = (__bf16)b.w;
    return r;
}

static __device__ __forceinline__ f32x4 exp4(f32x4 s) {
    f32x4 r;
    r[0] = __builtin_amdgcn_exp2f(s[0]);
    r[1] = __builtin_amdgcn_exp2f(s[1]);
    r[2] = __builtin_amdgcn_exp2f(s[2]);
    r[3] = __builtin_amdgcn_exp2f(s[3]);
    return r;
}

// adjacent-pair writes -> compiler can fuse into packed bf16 converts
static __device__ __forceinline__ bf16x8 pack8(f32x4 a, f32x4 b) {
    bf16x8 o;
    o[0] = (__bf16)a[0]; o[1] = (__bf16)a[1];
    o[2] = (__bf16)a[2]; o[3] = (__bf16)a[3];
    o[4] = (__bf16)b[0]; o[5] = (__bf16)b[1];
    o[6] = (__bf16)b[2]; o[7] = (__bf16)b[3];
    return o;
}

// ---------------------------------------------------------------------------
// Kernel 1: fused QKV projection, operand-SWAPPED MFMA (A=W rows, B=x rows).
// (unchanged — held control)
// ---------------------------------------------------------------------------
__global__ __launch_bounds__(256) void proj_qkv(
    const float* __restrict__ xq, const float* __restrict__ xk, const float* __restrict__ xv,
    const float* __restrict__ Wq, const float* __restrict__ Wk, const float* __restrict__ Wv,
    const float* __restrict__ bq, const float* __restrict__ bk, const float* __restrict__ bv,
    __bf16* __restrict__ Qs, __bf16* __restrict__ Kb, __bf16* __restrict__ Vt)
{
    __shared__ __align__(16) char wlds[34816];        // 128 rows x 272 B
    const int z = blockIdx.z;
    const float* x    = (z == 0) ? xq : ((z == 1) ? xk : xv);
    const float* Wf   = (z == 0) ? Wq : ((z == 1) ? Wk : Wv);
    const float* bias = (z == 0) ? bq : ((z == 1) ? bk : bv);
    const int b    = blockIdx.y;
    const int tid  = threadIdx.x;
    const int wave = tid >> 6, lane = tid & 63;
    const int quad = lane >> 4, l15 = lane & 15;
    const int n0   = blockIdx.x * 64 + wave * 16;

    {   // stage W (fp32 -> bf16) into LDS: thread = half-row
        const int r = tid >> 1, half = tid & 1;
        const float* wsrc = Wf + r * DIM + half * 64;
        char* wdst = wlds + r * 272 + half * 128;
        #pragma unroll
        for (int i = 0; i < 8; i++)
            *(bf16x8*)(wdst + i * 16) = cvt8(wsrc + i * 8);
    }

    bf16x8 a[4];
    const float* xrow = x + (b * N_SEQ + n0 + l15) * DIM + quad * 8;
    a[0] = cvt8(xrow);      a[1] = cvt8(xrow + 32);
    a[2] = cvt8(xrow + 64); a[3] = cvt8(xrow + 96);
    __syncthreads();

    const int n = n0 + l15;                    // D col = n (swapped)
    for (int t = 0; t < 8; t++) {
        const char* wr = wlds + (t * 16 + l15) * 272 + quad * 16;
        bf16x8 w0 = *(const bf16x8*)(wr);
        bf16x8 w1 = *(const bf16x8*)(wr + 64);
        bf16x8 w2 = *(const bf16x8*)(wr + 128);
        bf16x8 w3 = *(const bf16x8*)(wr + 192);

        f32x4 acc = {0.f, 0.f, 0.f, 0.f};
        acc = MFMA(w0, a[0], acc);
        acc = MFMA(w1, a[1], acc);
        acc = MFMA(w2, a[2], acc);
        acc = MFMA(w3, a[3], acc);

        const int d0 = t * 16 + quad * 4;      // D row = d0 + r
        if (z == 0) {
            const int h = d0 >> 5, dh0 = d0 & 31;
            bf16x4 q4;
            #pragma unroll
            for (int r = 0; r < 4; r++)
                q4[r] = (__bf16)((acc[r] + bias[d0 + r]) * QSCALE);
            *(bf16x4*)(Qs + ((b * NH + h) * N_SEQ + n) * DH + dh0) = q4;
        } else if (z == 1) {
            const int h = d0 >> 5, dh0 = d0 & 31;
            bf16x4 k4;
            #pragma unroll
            for (int r = 0; r < 4; r++)
                k4[r] = (__bf16)(acc[r] + bias[d0 + r]);
            *(bf16x4*)(Kb + ((b * NH + h) * N_SEQ + n) * DH + dh0) = k4;
        } else {
            const int nl = n & 63;
            const int np = (n & ~63) | (nl & 35) | ((nl & 12) << 1) | ((nl & 16) >> 2);
            #pragma unroll
            for (int r = 0; r < 4; r++) {
                const int d = d0 + r, h = d >> 5, dh = d & 31;
                Vt[((b * NH + h) * DH + dh) * N_SEQ + np] = (__bf16)(acc[r] + bias[d]);
            }
        }
    }
}

// ---------------------------------------------------------------------------
// Kernel 2: attention, 8-wave blocks = 2 query halves x 4-way split-K.
// Identical structure to R10; ONLY the launch bound changed (512,4)->(512,2).
// R10's (512,4) capped VGPR at 64 -> accumulator/fragment spill to scratch
// (FETCH 52MB, WRITE 94MB).  (512,2) caps at 256: compiler's natural ~140
// allocation fits, no spill; HW occupancy = min(LDS 2 blocks/CU -> 4
// waves/SIMD, VGPR ~3/SIMD) = 3-4 waves/SIMD vs R9's grid-limited 2.
// ---------------------------------------------------------------------------
__global__ __launch_bounds__(512, 2) void flash_attn(
    const __bf16* __restrict__ Qs, const __bf16* __restrict__ Kb,
    const __bf16* __restrict__ Vt, __bf16* __restrict__ ctxb)
{
    // K: 4 kh x 2 buf x 5120 = 40960 | V: 4 kh x 2 buf x 4608 = 36864
    // partials (post-loop, reuses K/V region): 2 qh x 3 kh x 64 lanes x 144
    __shared__ __align__(16) char smem[77824];
    char* const Kbase = smem;                  // + kh*10240 + cur*5120
    char* const Vbase = smem + 40960;          // + kh*9216  + cur*4608

    const int bid  = blockIdx.x;
    const int bh   = bid & 15;                 // consecutive blocks cycle heads
    const int qc   = bid >> 4;                 // 0..31, 128 queries each
    const int tid  = threadIdx.x;
    const int wave = tid >> 6, lane = tid & 63;
    const int quad = lane >> 4, l15 = lane & 15;
    const int qh   = wave & 1, kh = wave >> 1; // kh in 0..3
    const int n0   = qc * 128 + qh * 64;
    const int KH   = 1024;                     // keys per kh

    // Q B-fragments: 4 tiles of 16 queries
    const __bf16* Qp = Qs + (bh * N_SEQ + n0) * DH;
    bf16x8 qf[4];
    #pragma unroll
    for (int q = 0; q < 4; q++)
        qf[q] = *(const bf16x8*)(Qp + (q * 16 + l15) * DH + quad * 8);

    // staging: 512 threads cover 4 K-tiles + 4 V-tiles; thread does kh = khA, khA+2
    const int t8  = tid & 255, khA = tid >> 8;           // khA in {0,1}
    const int r_  = t8 >> 2,  c_  = t8 & 3;
    const __bf16* gK = Kb + (size_t)bh * N_SEQ * DH + (khA * KH + r_) * DH + c_ * 8;
    const __bf16* gV = Vt + ((size_t)bh * DH + (t8 >> 3)) * N_SEQ + khA * KH + (t8 & 7) * 8;
    const int kofsK = r_ * 80 + c_ * 16;
    const int kofsV = (t8 >> 3) * 144 + (t8 & 7) * 16;
    const int kStep2 = 2 * KH * DH;            // +2 kh groups in K elements
    char* const KldsA = Kbase + khA * 10240 + kofsK;
    char* const KldsB = Kbase + (khA + 2) * 10240 + kofsK;
    char* const VldsA = Vbase + khA * 9216 + kofsV;
    char* const VldsB = Vbase + (khA + 2) * 9216 + kofsV;

    {   // prologue: stage tile 0 of all 4 kh groups into buf 0
        bf16x8 k0 = *(const bf16x8*)(gK);
        bf16x8 k1 = *(const bf16x8*)(gK + kStep2);
        bf16x8 v0 = *(const bf16x8*)(gV);
        bf16x8 v1 = *(const bf16x8*)(gV + 2 * KH);
        *(bf16x8*)(KldsA) = k0;
        *(bf16x8*)(KldsB) = k1;
        *(bf16x8*)(VldsA) = v0;
        *(bf16x8*)(VldsB) = v1;
    }
    __syncthreads();

    char* const Kme = Kbase + kh * 10240;
    char* const Vme = Vbase + kh * 9216;

    f32x4 c[4][2];
    #pragma unroll
    for (int q = 0; q < 4; q++) { c[q][0] = f32x4{0.f,0.f,0.f,0.f}; c[q][1] = f32x4{0.f,0.f,0.f,0.f}; }
    float l[4] = {0.f, 0.f, 0.f, 0.f};
    const f32x4 z4 = {0.f,0.f,0.f,0.f};

    for (int kb = 0; kb < KH / 64; kb++) {     // 16 iters
        const int cur = kb & 1;
        const char* Kc = Kme + cur * 5120;
        const char* Vc = Vme + cur * 4608;

        // prefetch next 64-key tiles for all kh groups (wraps; harmless)
        const int kn = (kb + 1) & (KH / 64 - 1);
        bf16x8 krn0 = *(const bf16x8*)(gK + (size_t)(kn * 64) * DH);
        bf16x8 krn1 = *(const bf16x8*)(gK + (size_t)(kn * 64) * DH + kStep2);
        bf16x8 vrn0 = *(const bf16x8*)(gV + kn * 64);
        bf16x8 vrn1 = *(const bf16x8*)(gV + 2 * KH + kn * 64);

        // K A-frags (identity layout; rows 16b+l15)
        bf16x8 kf0 = *(const bf16x8*)(Kc + l15 * 80 + quad * 16);
        bf16x8 kf1 = *(const bf16x8*)(Kc + (16 + l15) * 80 + quad * 16);
        bf16x8 kf2 = *(const bf16x8*)(Kc + (32 + l15) * 80 + quad * 16);
        bf16x8 kf3 = *(const bf16x8*)(Kc + (48 + l15) * 80 + quad * 16);

        // scores + P (in registers) per query tile
        bf16x8 pf[4][2];
        #pragma unroll
        for (int q = 0; q < 4; q++) {
            f32x4 sa = MFMA(kf0, qf[q], z4);
            f32x4 sb = MFMA(kf1, qf[q], z4);
            f32x4 sc = MFMA(kf2, qf[q], z4);
            f32x4 sd = MFMA(kf3, qf[q], z4);
            f32x4 ea = exp4(sa), eb = exp4(sb), ec = exp4(sc), ed = exp4(sd);
            l[q] += ((ea[0]+ea[1])+(ea[2]+ea[3])) + ((eb[0]+eb[1])+(eb[2]+eb[3]))
                  + ((ec[0]+ec[1])+(ec[2]+ec[3])) + ((ed[0]+ed[1])+(ed[2]+ed[3]));
            pf[q][0] = pack8(ea, eb);          // keys g0
            pf[q][1] = pack8(ec, ed);          // keys g1
        }

        // V^T A-frags (stride 144, key-group g via +64)
        bf16x8 vf00 = *(const bf16x8*)(Vc + l15 * 144 + quad * 16);          // d0-15,  g0
        bf16x8 vf10 = *(const bf16x8*)(Vc + (16 + l15) * 144 + quad * 16);   // d16-31, g0
        bf16x8 vf01 = *(const bf16x8*)(Vc + l15 * 144 + 64 + quad * 16);     // d0-15,  g1
        bf16x8 vf11 = *(const bf16x8*)(Vc + (16 + l15) * 144 + 64 + quad * 16);

        #pragma unroll
        for (int q = 0; q < 4; q++) {
            c[q][0] = MFMA(vf00, pf[q][0], c[q][0]);
            c[q][1] = MFMA(vf10, pf[q][0], c[q][1]);
            c[q][0] = MFMA(vf01, pf[q][1], c[q][0]);
            c[q][1] = MFMA(vf11, pf[q][1], c[q][1]);
        }

        // stage next tiles into the other buffer
        *(bf16x8*)(KldsA + (cur ^ 1) * 5120) = krn0;
        *(bf16x8*)(KldsB + (cur ^ 1) * 5120) = krn1;
        *(bf16x8*)(VldsA + (cur ^ 1) * 4608) = vrn0;
        *(bf16x8*)(VldsB + (cur ^ 1) * 4608) = vrn1;
        __syncthreads();
    }

    // reduce l over quads (query = l15 preserved)
    #pragma unroll
    for (int q = 0; q < 4; q++) {
        l[q] += __shfl_xor(l[q], 16);
        l[q] += __shfl_xor(l[q], 32);
    }

    // split-K combine through (dead) K/V LDS region
    if (kh != 0) {
        char* dst = smem + ((qh * 3 + (kh - 1)) * 64 + lane) * 144;
        #pragma unroll
        for (int q = 0; q < 4; q++) {
            *(f32x4*)(dst + (q * 2 + 0) * 16) = c[q][0];
            *(f32x4*)(dst + (q * 2 + 1) * 16) = c[q][1];
        }
        f32x4 lv = {l[0], l[1], l[2], l[3]};
        *(f32x4*)(dst + 128) = lv;
    }
    __syncthreads();
    if (kh == 0) {
        #pragma unroll
        for (int m = 0; m < 3; m++) {
            const char* src = smem + ((qh * 3 + m) * 64 + lane) * 144;
            #pragma unroll
            for (int q = 0; q < 4; q++) {
                c[q][0] += *(const f32x4*)(src + (q * 2 + 0) * 16);
                c[q][1] += *(const f32x4*)(src + (q * 2 + 1) * 16);
            }
            f32x4 lp = *(const f32x4*)(src + 128);
            l[0] += lp[0]; l[1] += lp[1]; l[2] += lp[2]; l[3] += lp[3];
        }
        const int b = bh >> 2, h = bh & 3;
        #pragma unroll
        for (int q = 0; q < 4; q++) {
            const float inv = 1.0f / l[q];
            const int qg = n0 + q * 16 + l15;
            __bf16* dst = ctxb + ((size_t)(b * N_SEQ + qg)) * DIM + h * DH + quad * 4;
            #pragma unroll
            for (int dt = 0; dt < 2; dt++) {
                f32x4 cc = c[q][dt];
                bf16x2 e0 = {(__bf16)(cc[0] * inv), (__bf16)(cc[1] * inv)};
                bf16x2 e1 = {(__bf16)(cc[2] * inv), (__bf16)(cc[3] * inv)};
                *(bf16x2*)(dst + dt * 16)     = e0;
                *(bf16x2*)(dst + dt * 16 + 2) = e1;
            }
        }
    }
}

// ---------------------------------------------------------------------------
// Kernel 3: output projection, operand-swapped + Wo staged in LDS.
// (unchanged — held control)
// ---------------------------------------------------------------------------
__global__ __launch_bounds__(256) void out_proj(
    const __bf16* __restrict__ ctxb, const float* __restrict__ Wo,
    const float* __restrict__ bo, float* __restrict__ out)
{
    __shared__ __align__(16) char wlds[34816];
    const int b    = blockIdx.y;
    const int tid  = threadIdx.x;
    const int wave = tid >> 6, lane = tid & 63;
    const int quad = lane >> 4, l15 = lane & 15;
    const int n0   = blockIdx.x * 64 + wave * 16;

    {   // stage Wo (fp32 -> bf16) into LDS
        const int r = tid >> 1, half = tid & 1;
        const float* wsrc = Wo + r * DIM + half * 64;
        char* wdst = wlds + r * 272 + half * 128;
        #pragma unroll
        for (int i = 0; i < 8; i++)
            *(bf16x8*)(wdst + i * 16) = cvt8(wsrc + i * 8);
    }

    bf16x8 a[4];
    const __bf16* crow = ctxb + (b * N_SEQ + n0 + l15) * DIM + quad * 8;
    a[0] = *(const bf16x8*)(crow);
    a[1] = *(const bf16x8*)(crow + 32);
    a[2] = *(const bf16x8*)(crow + 64);
    a[3] = *(const bf16x8*)(crow + 96);
    __syncthreads();

    const int n = n0 + l15;
    for (int t = 0; t < 8; t++) {
        const char* wr = wlds + (t * 16 + l15) * 272 + quad * 16;
        bf16x8 w0 = *(const bf16x8*)(wr);
        bf16x8 w1 = *(const bf16x8*)(wr + 64);
        bf16x8 w2 = *(const bf16x8*)(wr + 128);
        bf16x8 w3 = *(const bf16x8*)(wr + 192);

        f32x4 acc = {0.f, 0.f, 0.f, 0.f};
        acc = MFMA(w0, a[0], acc);
        acc = MFMA(w1, a[1], acc);
        acc = MFMA(w2, a[2], acc);
        acc = MFMA(w3, a[3], acc);

        const int d0 = t * 16 + quad * 4;
        float4 o;
        o.x = acc[0] + bo[d0];
        o.y = acc[1] + bo[d0 + 1];
        o.z = acc[2] + bo[d0 + 2];
        o.w = acc[3] + bo[d0 + 3];
        *(float4*)(out + (b * N_SEQ + n) * DIM + d0) = o;
    }
}

// ---------------------------------------------------------------------------
extern "C" void kernel_launch(void* const* d_in, const int* in_sizes, int n_in,
                              void* d_out, int out_size, void* d_ws, size_t ws_size,
                              hipStream_t stream)
{
    const float* query = (const float*)d_in[0];
    const float* key   = (const float*)d_in[1];
    const float* value = (const float*)d_in[2];
    const float* Wq = (const float*)d_in[3];
    const float* bq = (const float*)d_in[4];
    const float* Wk = (const float*)d_in[5];
    const float* bk = (const float*)d_in[6];
    const float* Wv = (const float*)d_in[7];
    const float* bv = (const float*)d_in[8];
    const float* Wo = (const float*)d_in[9];
    const float* bo = (const float*)d_in[10];
    float* out = (float*)d_out;

    char* ws = (char*)d_ws;
    const size_t e = (size_t)BATCH * N_SEQ * DIM;   // 2,097,152 elements
    __bf16* Qs   = (__bf16*)(ws);                   // 4 MB  [B,H,N,32] scaled
    __bf16* Kb   = (__bf16*)(ws + 2 * e);           // 4 MB  [B,H,N,32] identity
    __bf16* Vt   = (__bf16*)(ws + 4 * e);           // 4 MB  [B,H,32,N] key-permuted
    __bf16* ctxb = (__bf16*)(ws + 6 * e);           // 4 MB  [B,N,128]

    proj_qkv<<<dim3(64, BATCH, 3), 256, 0, stream>>>(
        query, key, value, Wq, Wk, Wv, bq, bk, bv, Qs, Kb, Vt);
    flash_attn<<<dim3(512), 512, 0, stream>>>(Qs, Kb, Vt, ctxb);
    out_proj<<<dim3(64, BATCH), 256, 0, stream>>>(ctxb, Wo, bo, out);
}

// Round 12
// 149.650 us; speedup vs baseline: 1.3042x; 1.0497x over previous
//
#include <hip/hip_runtime.h>
#include <hip/hip_bf16.h>

#define N_SEQ 4096
#define DIM   128
#define NH    4
#define DH    32
#define BATCH 4

// scale = (1/sqrt(32)) * log2(e): softmax computed in exp2 domain
#define QSCALE 0.25503495870989204f

typedef __bf16 bf16x8 __attribute__((ext_vector_type(8)));
typedef __bf16 bf16x2 __attribute__((ext_vector_type(2)));
typedef __bf16 bf16x4 __attribute__((ext_vector_type(4)));
typedef float  f32x4  __attribute__((ext_vector_type(4)));

#define MFMA(a, b, c) __builtin_amdgcn_mfma_f32_16x16x32_bf16((a), (b), (c), 0, 0, 0)

static __device__ __forceinline__ bf16x8 cvt8(const float* __restrict__ p) {
    const float4* f4 = reinterpret_cast<const float4*>(p);
    float4 a = f4[0], b = f4[1];
    bf16x8 r;
    r[0] = (__bf16)a.x; r[1] = (__bf16)a.y; r[2] = (__bf16)a.z; r[3] = (__bf16)a.w;
    r[4] = (__bf16)b.x; r[5] = (__bf16)b.y; r[6] = (__bf16)b.z; r[7] = (__bf16)b.w;
    return r;
}

static __device__ __forceinline__ f32x4 exp4(f32x4 s) {
    f32x4 r;
    r[0] = __builtin_amdgcn_exp2f(s[0]);
    r[1] = __builtin_amdgcn_exp2f(s[1]);
    r[2] = __builtin_amdgcn_exp2f(s[2]);
    r[3] = __builtin_amdgcn_exp2f(s[3]);
    return r;
}

// adjacent-pair writes -> compiler can fuse into packed bf16 converts
static __device__ __forceinline__ bf16x8 pack8(f32x4 a, f32x4 b) {
    bf16x8 o;
    o[0] = (__bf16)a[0]; o[1] = (__bf16)a[1];
    o[2] = (__bf16)a[2]; o[3] = (__bf16)a[3];
    o[4] = (__bf16)b[0]; o[5] = (__bf16)b[1];
    o[6] = (__bf16)b[2]; o[7] = (__bf16)b[3];
    return o;
}

// ---------------------------------------------------------------------------
// Kernel 1: fused QKV projection, operand-SWAPPED MFMA (A=W rows, B=x rows).
// (unchanged — held control)
// ---------------------------------------------------------------------------
__global__ __launch_bounds__(256) void proj_qkv(
    const float* __restrict__ xq, const float* __restrict__ xk, const float* __restrict__ xv,
    const float* __restrict__ Wq, const float* __restrict__ Wk, const float* __restrict__ Wv,
    const float* __restrict__ bq, const float* __restrict__ bk, const float* __restrict__ bv,
    __bf16* __restrict__ Qs, __bf16* __restrict__ Kb, __bf16* __restrict__ Vt)
{
    __shared__ __align__(16) char wlds[34816];        // 128 rows x 272 B
    const int z = blockIdx.z;
    const float* x    = (z == 0) ? xq : ((z == 1) ? xk : xv);
    const float* Wf   = (z == 0) ? Wq : ((z == 1) ? Wk : Wv);
    const float* bias = (z == 0) ? bq : ((z == 1) ? bk : bv);
    const int b    = blockIdx.y;
    const int tid  = threadIdx.x;
    const int wave = tid >> 6, lane = tid & 63;
    const int quad = lane >> 4, l15 = lane & 15;
    const int n0   = blockIdx.x * 64 + wave * 16;

    {   // stage W (fp32 -> bf16) into LDS: thread = half-row
        const int r = tid >> 1, half = tid & 1;
        const float* wsrc = Wf + r * DIM + half * 64;
        char* wdst = wlds + r * 272 + half * 128;
        #pragma unroll
        for (int i = 0; i < 8; i++)
            *(bf16x8*)(wdst + i * 16) = cvt8(wsrc + i * 8);
    }

    bf16x8 a[4];
    const float* xrow = x + (b * N_SEQ + n0 + l15) * DIM + quad * 8;
    a[0] = cvt8(xrow);      a[1] = cvt8(xrow + 32);
    a[2] = cvt8(xrow + 64); a[3] = cvt8(xrow + 96);
    __syncthreads();

    const int n = n0 + l15;                    // D col = n (swapped)
    for (int t = 0; t < 8; t++) {
        const char* wr = wlds + (t * 16 + l15) * 272 + quad * 16;
        bf16x8 w0 = *(const bf16x8*)(wr);
        bf16x8 w1 = *(const bf16x8*)(wr + 64);
        bf16x8 w2 = *(const bf16x8*)(wr + 128);
        bf16x8 w3 = *(const bf16x8*)(wr + 192);

        f32x4 acc = {0.f, 0.f, 0.f, 0.f};
        acc = MFMA(w0, a[0], acc);
        acc = MFMA(w1, a[1], acc);
        acc = MFMA(w2, a[2], acc);
        acc = MFMA(w3, a[3], acc);

        const int d0 = t * 16 + quad * 4;      // D row = d0 + r
        if (z == 0) {
            const int h = d0 >> 5, dh0 = d0 & 31;
            bf16x4 q4;
            #pragma unroll
            for (int r = 0; r < 4; r++)
                q4[r] = (__bf16)((acc[r] + bias[d0 + r]) * QSCALE);
            *(bf16x4*)(Qs + ((b * NH + h) * N_SEQ + n) * DH + dh0) = q4;
        } else if (z == 1) {
            const int h = d0 >> 5, dh0 = d0 & 31;
            bf16x4 k4;
            #pragma unroll
            for (int r = 0; r < 4; r++)
                k4[r] = (__bf16)(acc[r] + bias[d0 + r]);
            *(bf16x4*)(Kb + ((b * NH + h) * N_SEQ + n) * DH + dh0) = k4;
        } else {
            const int nl = n & 63;
            const int np = (n & ~63) | (nl & 35) | ((nl & 12) << 1) | ((nl & 16) >> 2);
            #pragma unroll
            for (int r = 0; r < 4; r++) {
                const int d = d0 + r, h = d >> 5, dh = d & 31;
                Vt[((b * NH + h) * DH + dh) * N_SEQ + np] = (__bf16)(acc[r] + bias[d]);
            }
        }
    }
}

// ---------------------------------------------------------------------------
// Kernel 2: attention — R9 structure (4 waves: 2 query halves x 2-way
// split-K, 64 q/wave, P in registers) with 128-KEY SUPERBLOCKS: each LDS
// buffer holds TWO 64-key tiles, processed back-to-back with no barrier
// between -> barriers halve (32->16) and tile-1's ds_reads/S-MFMAs overlap
// tile-0's exp2 tail (cross-tile ILP the per-tile barrier forbade).
// K LDS tile 64x64B stride 80; V LDS tile 32x128B stride 144 (Vt key-
// permuted so score regs pack straight into the PV B-fragment via pack8).
// Split-K combine via the (dead) K LDS region post-loop.  No online max.
// grid = 512 (bh=bid&15), block = 256, LDS 77824 -> 2 blocks/CU.
// ---------------------------------------------------------------------------
__global__ __launch_bounds__(256, 2) void flash_attn(
    const __bf16* __restrict__ Qs, const __bf16* __restrict__ Kb,
    const __bf16* __restrict__ Vt, __bf16* __restrict__ ctxb)
{
    // K: 2 kh x 2 buf x 2 tiles x 5120 = 40960
    // V: 2 kh x 2 buf x 2 tiles x 4608 = 36864
    __shared__ __align__(16) char smem[77824];
    char* const Kbase = smem;                  // + kh*20480 + cur*10240 + t*5120
    char* const Vbase = smem + 40960;          // + kh*18432 + cur*9216  + t*4608

    const int bid  = blockIdx.x;
    const int bh   = bid & 15;                 // consecutive blocks cycle heads
    const int qc   = bid >> 4;                 // 0..31, 128 queries each
    const int tid  = threadIdx.x;
    const int wave = tid >> 6, lane = tid & 63;
    const int quad = lane >> 4, l15 = lane & 15;
    const int qh   = wave & 1, kh = wave >> 1; // kh in {0,1}
    const int n0   = qc * 128 + qh * 64;
    const int KH   = 2048;                     // keys per kh

    // Q B-fragments: 4 tiles of 16 queries
    const __bf16* Qp = Qs + (bh * N_SEQ + n0) * DH;
    bf16x8 qf[4];
    #pragma unroll
    for (int q = 0; q < 4; q++)
        qf[q] = *(const bf16x8*)(Qp + (q * 16 + l15) * DH + quad * 8);

    // staging: thread covers one 16B chunk of each tile (4 K + 4 V per superblock)
    const int r_ = tid >> 2, c_ = tid & 3;
    const __bf16* gK = Kb + (size_t)bh * N_SEQ * DH + r_ * DH + c_ * 8;
    const __bf16* gV = Vt + ((size_t)bh * DH + (tid >> 3)) * N_SEQ + (tid & 7) * 8;
    const int kofsK = r_ * 80 + c_ * 16;
    const int kofsV = (tid >> 3) * 144 + (tid & 7) * 16;

    {   // prologue: superblock 0 (2 tiles) of both kh groups -> buf 0
        #pragma unroll
        for (int g = 0; g < 2; g++) {
            #pragma unroll
            for (int t = 0; t < 2; t++) {
                bf16x8 kr = *(const bf16x8*)(gK + (size_t)(g * KH + t * 64) * DH);
                bf16x8 vr = *(const bf16x8*)(gV + g * KH + t * 64);
                *(bf16x8*)(Kbase + g * 20480 + t * 5120 + kofsK) = kr;
                *(bf16x8*)(Vbase + g * 18432 + t * 4608 + kofsV) = vr;
            }
        }
    }
    __syncthreads();

    char* const Kme = Kbase + kh * 20480;
    char* const Vme = Vbase + kh * 18432;

    f32x4 c[4][2];
    #pragma unroll
    for (int q = 0; q < 4; q++) { c[q][0] = f32x4{0.f,0.f,0.f,0.f}; c[q][1] = f32x4{0.f,0.f,0.f,0.f}; }
    float l[4] = {0.f, 0.f, 0.f, 0.f};
    const f32x4 z4 = {0.f,0.f,0.f,0.f};

    for (int kbb = 0; kbb < KH / 128; kbb++) { // 16 superblocks, 1 barrier each
        const int cur = kbb & 1;
        const char* Kc = Kme + cur * 10240;
        const char* Vc = Vme + cur * 9216;

        // prefetch next superblock for both kh groups (wraps; harmless)
        const int kn = (kbb + 1) & (KH / 128 - 1);
        bf16x8 krn[2][2], vrn[2][2];
        #pragma unroll
        for (int g = 0; g < 2; g++) {
            #pragma unroll
            for (int t = 0; t < 2; t++) {
                krn[g][t] = *(const bf16x8*)(gK + (size_t)(g * KH + kn * 128 + t * 64) * DH);
                vrn[g][t] = *(const bf16x8*)(gV + g * KH + kn * 128 + t * 64);
            }
        }

        #pragma unroll
        for (int t = 0; t < 2; t++) {          // two 64-key tiles, no barrier between
            const char* Kt  = Kc + t * 5120;
            const char* Vtl = Vc + t * 4608;

            // K A-frags (identity layout; rows 16i+l15)
            bf16x8 kf0 = *(const bf16x8*)(Kt + l15 * 80 + quad * 16);
            bf16x8 kf1 = *(const bf16x8*)(Kt + (16 + l15) * 80 + quad * 16);
            bf16x8 kf2 = *(const bf16x8*)(Kt + (32 + l15) * 80 + quad * 16);
            bf16x8 kf3 = *(const bf16x8*)(Kt + (48 + l15) * 80 + quad * 16);

            // scores + P (in registers) per query tile
            bf16x8 pf[4][2];
            #pragma unroll
            for (int q = 0; q < 4; q++) {
                f32x4 sa = MFMA(kf0, qf[q], z4);
                f32x4 sb = MFMA(kf1, qf[q], z4);
                f32x4 sc = MFMA(kf2, qf[q], z4);
                f32x4 sd = MFMA(kf3, qf[q], z4);
                f32x4 ea = exp4(sa), eb = exp4(sb), ec = exp4(sc), ed = exp4(sd);
                l[q] += ((ea[0]+ea[1])+(ea[2]+ea[3])) + ((eb[0]+eb[1])+(eb[2]+eb[3]))
                      + ((ec[0]+ec[1])+(ec[2]+ec[3])) + ((ed[0]+ed[1])+(ed[2]+ed[3]));
                pf[q][0] = pack8(ea, eb);      // keys g0
                pf[q][1] = pack8(ec, ed);      // keys g1
            }

            // V^T A-frags (stride 144, key-group via +64)
            bf16x8 vf00 = *(const bf16x8*)(Vtl + l15 * 144 + quad * 16);
            bf16x8 vf10 = *(const bf16x8*)(Vtl + (16 + l15) * 144 + quad * 16);
            bf16x8 vf01 = *(const bf16x8*)(Vtl + l15 * 144 + 64 + quad * 16);
            bf16x8 vf11 = *(const bf16x8*)(Vtl + (16 + l15) * 144 + 64 + quad * 16);

            #pragma unroll
            for (int q = 0; q < 4; q++) {
                c[q][0] = MFMA(vf00, pf[q][0], c[q][0]);
                c[q][1] = MFMA(vf10, pf[q][0], c[q][1]);
                c[q][0] = MFMA(vf01, pf[q][1], c[q][0]);
                c[q][1] = MFMA(vf11, pf[q][1], c[q][1]);
            }
        }

        // stage next superblock into the other buffer
        #pragma unroll
        for (int g = 0; g < 2; g++) {
            #pragma unroll
            for (int t = 0; t < 2; t++) {
                *(bf16x8*)(Kbase + g * 20480 + (cur ^ 1) * 10240 + t * 5120 + kofsK) = krn[g][t];
                *(bf16x8*)(Vbase + g * 18432 + (cur ^ 1) * 9216 + t * 4608 + kofsV) = vrn[g][t];
            }
        }
        __syncthreads();
    }

    // reduce l over quads (query = l15 preserved)
    #pragma unroll
    for (int q = 0; q < 4; q++) {
        l[q] += __shfl_xor(l[q], 16);
        l[q] += __shfl_xor(l[q], 32);
    }

    // split-K combine via the dead K LDS region
    if (kh == 1) {
        char* dst = smem + (qh * 64 + lane) * 144;
        #pragma unroll
        for (int q = 0; q < 4; q++) {
            *(f32x4*)(dst + (q * 2 + 0) * 16) = c[q][0];
            *(f32x4*)(dst + (q * 2 + 1) * 16) = c[q][1];
        }
        f32x4 lv = {l[0], l[1], l[2], l[3]};
        *(f32x4*)(dst + 128) = lv;
    }
    __syncthreads();
    if (kh == 0) {
        const char* src = smem + (qh * 64 + lane) * 144;
        f32x4 lp = *(const f32x4*)(src + 128);
        const int b = bh >> 2, h = bh & 3;
        #pragma unroll
        for (int q = 0; q < 4; q++) {
            c[q][0] += *(const f32x4*)(src + (q * 2 + 0) * 16);
            c[q][1] += *(const f32x4*)(src + (q * 2 + 1) * 16);
            const float inv = 1.0f / (l[q] + lp[q]);
            const int qg = n0 + q * 16 + l15;
            __bf16* dst = ctxb + ((size_t)(b * N_SEQ + qg)) * DIM + h * DH + quad * 4;
            #pragma unroll
            for (int dt = 0; dt < 2; dt++) {
                f32x4 cc = c[q][dt];
                bf16x2 e0 = {(__bf16)(cc[0] * inv), (__bf16)(cc[1] * inv)};
                bf16x2 e1 = {(__bf16)(cc[2] * inv), (__bf16)(cc[3] * inv)};
                *(bf16x2*)(dst + dt * 16)     = e0;
                *(bf16x2*)(dst + dt * 16 + 2) = e1;
            }
        }
    }
}

// ---------------------------------------------------------------------------
// Kernel 3: output projection, operand-swapped + Wo staged in LDS.
// (unchanged — held control)
// ---------------------------------------------------------------------------
__global__ __launch_bounds__(256) void out_proj(
    const __bf16* __restrict__ ctxb, const float* __restrict__ Wo,
    const float* __restrict__ bo, float* __restrict__ out)
{
    __shared__ __align__(16) char wlds[34816];
    const int b    = blockIdx.y;
    const int tid  = threadIdx.x;
    const int wave = tid >> 6, lane = tid & 63;
    const int quad = lane >> 4, l15 = lane & 15;
    const int n0   = blockIdx.x * 64 + wave * 16;

    {   // stage Wo (fp32 -> bf16) into LDS
        const int r = tid >> 1, half = tid & 1;
        const float* wsrc = Wo + r * DIM + half * 64;
        char* wdst = wlds + r * 272 + half * 128;
        #pragma unroll
        for (int i = 0; i < 8; i++)
            *(bf16x8*)(wdst + i * 16) = cvt8(wsrc + i * 8);
    }

    bf16x8 a[4];
    const __bf16* crow = ctxb + (b * N_SEQ + n0 + l15) * DIM + quad * 8;
    a[0] = *(const bf16x8*)(crow);
    a[1] = *(const bf16x8*)(crow + 32);
    a[2] = *(const bf16x8*)(crow + 64);
    a[3] = *(const bf16x8*)(crow + 96);
    __syncthreads();

    const int n = n0 + l15;
    for (int t = 0; t < 8; t++) {
        const char* wr = wlds + (t * 16 + l15) * 272 + quad * 16;
        bf16x8 w0 = *(const bf16x8*)(wr);
        bf16x8 w1 = *(const bf16x8*)(wr + 64);
        bf16x8 w2 = *(const bf16x8*)(wr + 128);
        bf16x8 w3 = *(const bf16x8*)(wr + 192);

        f32x4 acc = {0.f, 0.f, 0.f, 0.f};
        acc = MFMA(w0, a[0], acc);
        acc = MFMA(w1, a[1], acc);
        acc = MFMA(w2, a[2], acc);
        acc = MFMA(w3, a[3], acc);

        const int d0 = t * 16 + quad * 4;
        float4 o;
        o.x = acc[0] + bo[d0];
        o.y = acc[1] + bo[d0 + 1];
        o.z = acc[2] + bo[d0 + 2];
        o.w = acc[3] + bo[d0 + 3];
        *(float4*)(out + (b * N_SEQ + n) * DIM + d0) = o;
    }
}

// ---------------------------------------------------------------------------
extern "C" void kernel_launch(void* const* d_in, const int* in_sizes, int n_in,
                              void* d_out, int out_size, void* d_ws, size_t ws_size,
                              hipStream_t stream)
{
    const float* query = (const float*)d_in[0];
    const float* key   = (const float*)d_in[1];
    const float* value = (const float*)d_in[2];
    const float* Wq = (const float*)d_in[3];
    const float* bq = (const float*)d_in[4];
    const float* Wk = (const float*)d_in[5];
    const float* bk = (const float*)d_in[6];
    const float* Wv = (const float*)d_in[7];
    const float* bv = (const float*)d_in[8];
    const float* Wo = (const float*)d_in[9];
    const float* bo = (const float*)d_in[10];
    float* out = (float*)d_out;

    char* ws = (char*)d_ws;
    const size_t e = (size_t)BATCH * N_SEQ * DIM;   // 2,097,152 elements
    __bf16* Qs   = (__bf16*)(ws);                   // 4 MB  [B,H,N,32] scaled
    __bf16* Kb   = (__bf16*)(ws + 2 * e);           // 4 MB  [B,H,N,32] identity
    __bf16* Vt   = (__bf16*)(ws + 4 * e);           // 4 MB  [B,H,32,N] key-permuted
    __bf16* ctxb = (__bf16*)(ws + 6 * e);           // 4 MB  [B,N,128]

    proj_qkv<<<dim3(64, BATCH, 3), 256, 0, stream>>>(
        query, key, value, Wq, Wk, Wv, bq, bk, bv, Qs, Kb, Vt);
    flash_attn<<<dim3(512), 256, 0, stream>>>(Qs, Kb, Vt, ctxb);
    out_proj<<<dim3(64, BATCH), 256, 0, stream>>>(ctxb, Wo, bo, out);
}